// Round 7
// baseline (1310.911 us; speedup 1.0000x reference)
//
#include <hip/hip_runtime.h>

// ---------------------------------------------------------------------------
// BiSSM global block, MI355X — round 7: log-doubling, counted-vmcnt pipeline.
//   u[t]    = xn[t]@Bm^T (dup to fwd+bwd halves)            k_gemm<0>
//   X_2k[t] = X_k[t] + X_k[t-/+k]@(A^k)^T, k=1..512          k_gemm<0> x10
//   Xsum[t] = X_f[t]+X_f[t-1024]@W + X_b[t]+X_b[t+1024]@W    k_gemm<1> (W=A^1024)
//   y       = Xsum@Cm^T                                      k_gemm<0>
//   out     = x + alpha*0.5*y*sigmoid(xn@gw^T+gb)            k_gemm<2>
// GEMM core: 128x128 tile, BK=32, NBUF-ring LDS (MODE0/2: 4 bufs, 3-step
// lookahead, s_waitcnt vmcnt(8) -> never drains in steady state; MODE1:
// 3 bufs, vmcnt(6)), ONE raw s_barrier per K-step. global_load_lds(16B)
// with chunk swizzle c^((r^(r>>2))&3). Epilogue: acc -> LDS bounce with
// PAD-132 stride (conflict-free b32 write / b128 read) -> vectorized I/O.
// Powers A^2..A^1024: hi/lo-bf16 f32 squaring chain (k_sq x10).
// ---------------------------------------------------------------------------

typedef short  bfrag __attribute__((ext_vector_type(8)));   // 8 x bf16
typedef float  ffrag __attribute__((ext_vector_type(4)));   // mfma acc
typedef float  f4    __attribute__((ext_vector_type(4)));
typedef short  s4v   __attribute__((ext_vector_type(4)));   // 4 x bf16

#define DEV static __device__ __forceinline__
#define Hn 768
#define FLS 132   // f32 epilogue bounce row stride (pad: 128 + 4)

DEV unsigned short f2bf(float f) {
  unsigned u = __float_as_uint(f);
  u += 0x7fffu + ((u >> 16) & 1u);            // round-to-nearest-even
  return (unsigned short)(u >> 16);
}
DEV float bf2f(unsigned short s) { return __uint_as_float(((unsigned)s) << 16); }

DEV ffrag mfma16(bfrag a, bfrag b, ffrag c) {
  return __builtin_amdgcn_mfma_f32_16x16x32_bf16(a, b, c, 0, 0, 0);
}

DEV void glds16(const unsigned short* g, unsigned short* l) {
  __builtin_amdgcn_global_load_lds(
      (const __attribute__((address_space(1))) unsigned int*)g,
      (__attribute__((address_space(3))) unsigned int*)l, 16, 0, 0);
}

template<int N> DEV void vwait() {
  if constexpr (N == 0)       asm volatile("s_waitcnt vmcnt(0)" ::: "memory");
  else if constexpr (N == 4)  asm volatile("s_waitcnt vmcnt(4)" ::: "memory");
  else if constexpr (N == 6)  asm volatile("s_waitcnt vmcnt(6)" ::: "memory");
  else if constexpr (N == 8)  asm volatile("s_waitcnt vmcnt(8)" ::: "memory");
  else if constexpr (N == 12) asm volatile("s_waitcnt vmcnt(12)" ::: "memory");
}

union BF8 { bfrag v; unsigned short u[8]; };

// ---------------------------------------------------------------------------
// k_abuild: gridDim = (768, 4); task = blockIdx.y
__global__ __launch_bounds__(256) void k_abuild(
    const float* __restrict__ U, const float* __restrict__ V,
    const float* __restrict__ S, const float* __restrict__ Bm,
    const float* __restrict__ Cm, const float* __restrict__ gw,
    float* __restrict__ Af, float* __restrict__ AfT,
    unsigned short* __restrict__ Abf,
    unsigned short* __restrict__ Bmb, unsigned short* __restrict__ Cmb,
    unsigned short* __restrict__ gwb, unsigned short* __restrict__ zp) {
  int i = blockIdx.x;
  int task = blockIdx.y;
  if (task == 0) {
    float u0 = U[i*4+0], u1 = U[i*4+1], u2 = U[i*4+2], u3 = U[i*4+3];
    for (int j = threadIdx.x; j < Hn; j += 256) {
      float a = u0*V[j*4+0] + u1*V[j*4+1] + u2*V[j*4+2] + u3*V[j*4+3]
              + S[i*Hn+j] - S[j*Hn+i];
      if (i == j) a += -(float)(i+1) / 768.0f;
      Af[i*Hn+j]  = a;
      AfT[j*Hn+i] = a;
      Abf[i*Hn+j] = f2bf(a);
    }
    if (i == 0) for (int j = threadIdx.x; j < 1024; j += 256) zp[j] = 0;
  } else {
    const float* src = (task==1) ? Bm : (task==2) ? Cm : gw;
    unsigned short* dst = (task==1) ? Bmb : (task==2) ? Cmb : gwb;
    for (int j = threadIdx.x; j < Hn; j += 256) dst[i*Hn+j] = f2bf(src[i*Hn+j]);
  }
}

// ---------------------------------------------------------------------------
// k_rms: one wave per row (row = b*2048 + t); write xn in (t,b) order, bf16.
__global__ __launch_bounds__(256) void k_rms(
    const float* __restrict__ x, const float* __restrict__ scale,
    unsigned short* __restrict__ xn) {
  int row  = blockIdx.x * 4 + (threadIdx.x >> 6);
  int lane = threadIdx.x & 63;
  int b = row >> 11, t = row & 2047;
  const float* xr = x + (long)row * Hn;
  float v[12];
  float ss = 0.f;
#pragma unroll
  for (int j = 0; j < 12; ++j) { v[j] = xr[lane + j*64]; ss += v[j]*v[j]; }
#pragma unroll
  for (int off = 1; off < 64; off <<= 1) ss += __shfl_xor(ss, off);
  float inv = 1.0f / sqrtf(ss / 768.0f + 1e-8f);
  unsigned short* dst = xn + ((long)t * 8 + b) * Hn;
#pragma unroll
  for (int j = 0; j < 12; ++j) dst[lane + j*64] = f2bf(v[j] * inv * scale[lane + j*64]);
}

// ---------------------------------------------------------------------------
// k_sq: Z = X @ X, hi/lo bf16 (3 passes). Writes Z rm + Z^T rm f32 + bf16.
// grid (12, 6), 512 thr, tile 64x128.
__global__ __launch_bounds__(512) void k_sq(
    const float* __restrict__ X, const float* __restrict__ XT,
    float* __restrict__ Z, float* __restrict__ ZT,
    unsigned short* __restrict__ Zbf) {
  int tid = threadIdx.x, lane = tid & 63, w = tid >> 6;
  int mw = w >> 2, nw = w & 3, l15 = lane & 15, lhi = lane >> 4;
  int rb = blockIdx.x * 64, cb = blockIdx.y * 128;
  ffrag acc[2][2] = {};
  for (int kt = 0; kt < 24; ++kt) {
    int k0 = kt*32 + lhi*8;
    BF8 ah[2], al[2], bh[2], bl[2];
#pragma unroll
    for (int mt = 0; mt < 2; ++mt) {
      const f4* p = (const f4*)(X + (long)(rb + mw*32 + mt*16 + l15) * Hn + k0);
      f4 x0 = p[0], x1 = p[1];
#pragma unroll
      for (int j = 0; j < 8; ++j) {
        float f = (j < 4) ? x0[j] : x1[j-4];
        unsigned short h = f2bf(f);
        ah[mt].u[j] = h; al[mt].u[j] = f2bf(f - bf2f(h));
      }
    }
#pragma unroll
    for (int nt = 0; nt < 2; ++nt) {
      const f4* p = (const f4*)(XT + (long)(cb + nw*32 + nt*16 + l15) * Hn + k0);
      f4 x0 = p[0], x1 = p[1];
#pragma unroll
      for (int j = 0; j < 8; ++j) {
        float f = (j < 4) ? x0[j] : x1[j-4];
        unsigned short h = f2bf(f);
        bh[nt].u[j] = h; bl[nt].u[j] = f2bf(f - bf2f(h));
      }
    }
#pragma unroll
    for (int mt = 0; mt < 2; ++mt)
#pragma unroll
      for (int nt = 0; nt < 2; ++nt) {
        acc[mt][nt] = mfma16(ah[mt].v, bh[nt].v, acc[mt][nt]);
        acc[mt][nt] = mfma16(ah[mt].v, bl[nt].v, acc[mt][nt]);
        acc[mt][nt] = mfma16(al[mt].v, bh[nt].v, acc[mt][nt]);
      }
  }
#pragma unroll
  for (int mt = 0; mt < 2; ++mt)
#pragma unroll
    for (int nt = 0; nt < 2; ++nt)
#pragma unroll
      for (int q = 0; q < 4; ++q) {
        int grow = rb + mw*32 + mt*16 + lhi*4 + q;
        int gcol = cb + nw*32 + nt*16 + l15;
        float vv = acc[mt][nt][q];
        Z[(long)grow*Hn + gcol] = vv;
        ZT[(long)gcol*Hn + grow] = vv;
        Zbf[(long)grow*Hn + gcol] = f2bf(vv);
      }
}

// ---------------------------------------------------------------------------
// k_gemm<MODE>: 128x128 tile, BK=32, 24 K-steps, 256 thr (4 waves, 2x2 of
// 64x64). Counted-vmcnt ring pipeline (see header). Chunk swizzle:
// c ^ ((r ^ (r>>2)) & 3).
// MODE 0: outb = [res +] A0[row -/+ sh] @ B0^T ; dup -> also write +16384.
// MODE 1: outb[r] = res[r]+res[r+16384] + (A0[r-sh] + A0[r+16384+sh]) @ B0^T
// MODE 2: outf = x + alpha*0.5*yb*sigmoid(A0@B0^T + gb)   (row = t*8+b)
template<int MODE>
__global__ __launch_bounds__(256) void k_gemm(
    const unsigned short* __restrict__ A0s, const unsigned short* __restrict__ B0s,
    const unsigned short* __restrict__ res, unsigned short* __restrict__ outb,
    const unsigned short* __restrict__ zp, int sh, int dup,
    const unsigned short* __restrict__ yb,
    const float* __restrict__ gb, const float* __restrict__ alpha,
    const float* __restrict__ x, float* __restrict__ outf) {
  constexpr int NA   = (MODE == 1) ? 2 : 1;     // A streams
  constexpr int NT   = NA + 1;                  // tiles per step (A.. + B)
  constexpr int NBUF = (MODE == 1) ? 3 : 4;     // LDS ring depth
  constexpr int LA   = NBUF - 1;                // lookahead (tiles ahead)
  constexpr int NL   = 2 * NT;                  // glds16 per wave per step

  __shared__ __align__(16) char smem[NBUF * NT * 8192];
  unsigned short* ldsb = (unsigned short*)smem;

  const int tid = threadIdx.x, lane = tid & 63, w = tid >> 6;
  const int l15 = lane & 15, lhi = lane >> 4;
  const int wr = w >> 1, wc = w & 1;

  // XCD-aware bijective block swizzle (m204), col-fast decompose (ncol=6).
  const int nwg = gridDim.x;
  const int q8 = nwg >> 3, r8 = nwg & 7, xcd = blockIdx.x & 7, fo = blockIdx.x >> 3;
  const int wg = (xcd < r8 ? xcd*(q8+1) : r8*(q8+1) + (xcd - r8)*q8) + fo;
  const int cb = wg % 6, rbk = wg / 6;
  const long r0 = (long)rbk * 128;
  const long bc0 = (long)cb * 128;
  const int dir = (MODE == 0 && r0 >= 16384) ? 1 : 0;

  bool skip = false;
  if (MODE == 0 && sh > 0)
    skip = dir ? (r0 >= 32768 - sh) : (r0 + 128 <= sh);

  // staging geometry: inst = w*2+jj covers rows inst*16..+15 (1KB each);
  // lane: rowin = lane>>2, chunk ch = lane&3; source chunk c = ch ^ XS(r).
  const int rowin = lane >> 2, ch = lane & 3;
  long gA[NA][2]; bool vA[NA][2]; long gB[2]; int lbase[2];
#pragma unroll
  for (int jj = 0; jj < 2; ++jj) {
    const int inst = w*2 + jj;
    const int r = inst*16 + rowin;
    const int c = ch ^ ((r ^ (r >> 2)) & 3);
    lbase[jj] = inst * 512;
#pragma unroll
    for (int s = 0; s < NA; ++s) {
      long gr; bool ok = true;
      if (MODE == 0) {
        gr = r0 + r + (dir ? sh : -sh);
        ok = dir ? (gr < 32768) : (gr >= 0);
      } else if (MODE == 1) {
        if (s == 0) { gr = r0 + r - sh; ok = (gr >= 0); }
        else        { gr = r0 + r + 16384 + sh; ok = (gr < 32768); }
      } else {
        gr = r0 + r;
      }
      vA[s][jj] = ok; gA[s][jj] = gr * Hn + c*8;
    }
    gB[jj] = (bc0 + r) * Hn + c*8;
  }

  auto stage = [&](int buf, int kt) {
    const int ko = kt * 32;
    unsigned short* dst = ldsb + buf * (NT * 4096);
#pragma unroll
    for (int jj = 0; jj < 2; ++jj) {
#pragma unroll
      for (int s = 0; s < NA; ++s) {
        const unsigned short* g = vA[s][jj] ? (A0s + gA[s][jj] + ko) : zp;
        glds16(g, dst + s*4096 + lbase[jj]);
      }
      glds16(B0s + gB[jj] + ko, dst + NA*4096 + lbase[jj]);
    }
  };

  ffrag acc[4][4] = {};
  const int cx = (lhi ^ ((l15 ^ (l15 >> 2)) & 3)) * 8;   // swizzled read chunk

  if (!skip) {
#pragma unroll
    for (int t = 0; t < LA; ++t) stage(t, t);   // prologue: tiles 0..LA-1
    int cur = 0, nb = LA;
    for (int kt = 0; kt < 24; ++kt) {
      const int rem = 23 - kt;                  // tiles staged beyond kt
      if (rem >= LA - 1) vwait<NL * (LA - 1)>();
      else if (rem == 1) vwait<NL>();
      else               vwait<0>();
      __builtin_amdgcn_s_barrier();             // tile kt visible to all waves
      const unsigned short* L = ldsb + cur * (NT * 4096);
      bfrag a[NA][4], b[4];
#pragma unroll
      for (int mt = 0; mt < 4; ++mt) {
        const int row = wr*64 + mt*16 + l15;
#pragma unroll
        for (int s = 0; s < NA; ++s)
          a[s][mt] = *(const bfrag*)&L[s*4096 + row*32 + cx];
      }
#pragma unroll
      for (int nt = 0; nt < 4; ++nt) {
        const int row = wc*64 + nt*16 + l15;
        b[nt] = *(const bfrag*)&L[NA*4096 + row*32 + cx];
      }
#pragma unroll
      for (int mt = 0; mt < 4; ++mt)
#pragma unroll
        for (int nt = 0; nt < 4; ++nt) {
          acc[mt][nt] = mfma16(a[0][mt], b[nt], acc[mt][nt]);
          if (NA == 2) acc[mt][nt] = mfma16(a[1][mt], b[nt], acc[mt][nt]);
        }
      if (kt + LA <= 23) stage(nb, kt + LA);    // refill ring (never buf 'cur')
      cur = (cur == NBUF-1) ? 0 : cur + 1;
      nb  = (nb  == NBUF-1) ? 0 : nb  + 1;
    }
  }

  // ------ epilogue: acc -> LDS bounce (f32, pad FLS) -> vectorized I/O ------
  float* fl = (float*)smem;                 // 64 rows x FLS f32 = 33792 B
  const float al = (MODE == 2) ? alpha[0] : 0.f;
#pragma unroll
  for (int hh = 0; hh < 2; ++hh) {
    __syncthreads();
    if (wr == hh) {
#pragma unroll
      for (int mt = 0; mt < 4; ++mt)
#pragma unroll
        for (int nt = 0; nt < 4; ++nt)
#pragma unroll
          for (int q = 0; q < 4; ++q)
            fl[(mt*16 + lhi*4 + q)*FLS + wc*64 + nt*16 + l15] = acc[mt][nt][q];
    }
    __syncthreads();
    for (int i = tid; i < 2048; i += 256) {
      const int row = i >> 5;
      const int cc  = (i & 31) << 2;
      f4 v = *(const f4*)&fl[row*FLS + cc];
      const long grow = r0 + hh*64 + row;
      const long gcol = bc0 + cc;
      const long go = grow * Hn + gcol;
      if (MODE == 0) {
        if (res) {
          s4v rv = *(const s4v*)&res[go];
#pragma unroll
          for (int j = 0; j < 4; ++j) v[j] += bf2f(((unsigned short*)&rv)[j]);
        }
        s4v ov;
#pragma unroll
        for (int j = 0; j < 4; ++j) ((unsigned short*)&ov)[j] = f2bf(v[j]);
        *(s4v*)&outb[go] = ov;
        if (dup) *(s4v*)&outb[go + (long)16384*Hn] = ov;
      } else if (MODE == 1) {
        s4v ra = *(const s4v*)&res[go];
        s4v rb2 = *(const s4v*)&res[go + (long)16384*Hn];
#pragma unroll
        for (int j = 0; j < 4; ++j)
          v[j] += bf2f(((unsigned short*)&ra)[j]) + bf2f(((unsigned short*)&rb2)[j]);
        s4v ov;
#pragma unroll
        for (int j = 0; j < 4; ++j) ((unsigned short*)&ov)[j] = f2bf(v[j]);
        *(s4v*)&outb[go] = ov;
      } else {
        f4 gbv = *(const f4*)&gb[gcol];
        s4v yv = *(const s4v*)&yb[go];
        const long t = grow >> 3, b = grow & 7;
        const long o = (b*2048 + t)*Hn + gcol;
        f4 xv = *(const f4*)&x[o];
        f4 ov;
#pragma unroll
        for (int j = 0; j < 4; ++j) {
          float z = v[j] + gbv[j];
          float g = 1.0f / (1.0f + __expf(-z));
          ov[j] = xv[j] + al * 0.5f * bf2f(((unsigned short*)&yv)[j]) * g;
        }
        *(f4*)&outf[o] = ov;
      }
    }
  }
}

// ---------------------------------------------------------------------------
extern "C" void kernel_launch(void* const* d_in, const int* in_sizes, int n_in,
                              void* d_out, int out_size, void* d_ws, size_t ws_size,
                              hipStream_t stream) {
  const float* x     = (const float*)d_in[0];
  const float* scale = (const float*)d_in[1];
  const float* U     = (const float*)d_in[2];
  const float* V     = (const float*)d_in[3];
  const float* S     = (const float*)d_in[4];
  const float* Bm    = (const float*)d_in[5];
  const float* Cm    = (const float*)d_in[6];
  const float* gw    = (const float*)d_in[7];
  const float* gb    = (const float*)d_in[8];
  const float* alpha = (const float*)d_in[9];
  float* out = (float*)d_out;

  char* p = (char*)d_ws;
  auto alloc = [&](size_t sz) { char* r = p; p += (sz + 255) & ~(size_t)255; return r; };

  const size_t SZ_X  = (size_t)32768 * Hn * sizeof(unsigned short);  // 50.3MB
  const size_t SZ_BF = (size_t)16384 * Hn * sizeof(unsigned short);  // 25.2MB
  const size_t SZ_M  = (size_t)Hn * Hn * sizeof(float);              // 2.36MB
  const size_t SZ_MB = (size_t)Hn * Hn * sizeof(unsigned short);     // 1.18MB

  unsigned short* xn = (unsigned short*)alloc(SZ_BF);
  unsigned short* XA = (unsigned short*)alloc(SZ_X);
  unsigned short* XB = (unsigned short*)alloc(SZ_X);
  float* Af  = (float*)alloc(SZ_M);
  float* AfT = (float*)alloc(SZ_M);
  float* P1  = (float*)alloc(SZ_M);
  float* P1T = (float*)alloc(SZ_M);
  float* P2  = (float*)alloc(SZ_M);
  float* P2T = (float*)alloc(SZ_M);
  unsigned short* Abf = (unsigned short*)alloc(SZ_MB);
  unsigned short* Ab[10];                      // A^2..A^1024 bf16
  for (int i = 0; i < 10; ++i) Ab[i] = (unsigned short*)alloc(SZ_MB);
  unsigned short* Bmb = (unsigned short*)alloc(SZ_MB);
  unsigned short* Cmb = (unsigned short*)alloc(SZ_MB);
  unsigned short* gwb = (unsigned short*)alloc(SZ_MB);
  unsigned short* zp  = (unsigned short*)alloc(1024 * sizeof(unsigned short));

  if ((size_t)(p - (char*)d_ws) > ws_size) return;  // workspace too small

  k_abuild<<<dim3(768, 4), 256, 0, stream>>>(U, V, S, Bm, Cm, gw,
      Af, AfT, Abf, Bmb, Cmb, gwb, zp);
  k_rms<<<4096, 256, 0, stream>>>(x, scale, xn);

  // squaring chain: A -> A^2 -> ... -> A^1024 (bf16 emitted each step)
  const float* sx = Af; const float* sxt = AfT;
  float* za = P1; float* zat = P1T; float* zb = P2; float* zbt = P2T;
  for (int i = 0; i < 10; ++i) {
    k_sq<<<dim3(12, 6), 512, 0, stream>>>(sx, sxt, za, zat, Ab[i]);
    sx = za; sxt = zat;
    float* t1 = za; float* t2 = zat; za = zb; zat = zbt; zb = t1; zbt = t2;
  }

  // u = xn@Bm^T, duplicated into fwd+bwd halves of XA
  k_gemm<0><<<768, 256, 0, stream>>>(xn, Bmb, nullptr, XA, zp, 0, 1,
      nullptr, nullptr, nullptr, nullptr, nullptr);

  // doubling levels k=1..512 (shift sh=8k rows)
  unsigned short* src = XA; unsigned short* dst = XB;
  for (int i = 0; i < 10; ++i) {
    const unsigned short* W = (i == 0) ? Abf : Ab[i-1];
    k_gemm<0><<<1536, 256, 0, stream>>>(src, W, src, dst, zp, 8 << i, 0,
        nullptr, nullptr, nullptr, nullptr, nullptr);
    unsigned short* t = src; src = dst; dst = t;
  }
  // src holds X_1024 (both dirs). Last level (k=1024) + fwd/bwd sum:
  k_gemm<1><<<768, 256, 0, stream>>>(src, Ab[9], src, XB, zp, 8192, 0,
      nullptr, nullptr, nullptr, nullptr, nullptr);

  // y = Xsum@Cm^T
  unsigned short* ybuf = XB + (size_t)16384 * Hn;
  k_gemm<0><<<768, 256, 0, stream>>>(XB, Cmb, nullptr, ybuf, zp, 0, 0,
      nullptr, nullptr, nullptr, nullptr, nullptr);

  // out = x + alpha*0.5*y*sigmoid(xn@gw^T+gb)
  k_gemm<2><<<768, 256, 0, stream>>>(xn, gwb, nullptr, nullptr, zp, 0, 0,
      ybuf, gb, alpha, x, out);
}

// Round 8
// 1262.272 us; speedup vs baseline: 1.0385x; 1.0385x over previous
//
#include <hip/hip_runtime.h>

// ---------------------------------------------------------------------------
// BiSSM global block, MI355X — round 8: log-doubling, NBUF=3 counted pipeline
// at 3 blocks/CU + fused final (y-GEMM merged into gate kernel).
//   u[t]    = xn[t]@Bm^T (dup to fwd+bwd halves)            k_gemm<0>
//   X_2k[t] = X_k[t] + X_k[t-/+k]@(A^k)^T, k=1..512          k_gemm<0> x10
//   Xsum[t] = X_f[t]+X_f[t-1024]@W + X_b[t]+X_b[t+1024]@W    k_gemm<1> (W=A^1024)
//   out     = x + alpha*0.5*(Xsum@Cm^T)*sigmoid(xn@gw^T+gb)  k_gemm<2> (dual GEMM)
// GEMM core: 128x128 tile, BK=32. MODE0: 3-buf ring (48KB LDS -> 3 blocks/CU),
// stage(kt+2) AFTER barrier (race-free), steady vmcnt(4), drain only at tail.
// MODE1/2: 2-buf (48/64KB), vmcnt(0)+barrier+stage(kt+1) (loads fly across one
// compute phase). global_load_lds(16B), chunk swizzle c^((r^(r>>2))&3).
// Epilogue: acc -> LDS bounce stride-132 -> vectorized global I/O.
// Powers A^2..A^1024: hi/lo-bf16 f32 squaring chain (k_sq x10).
// ---------------------------------------------------------------------------

typedef short  bfrag __attribute__((ext_vector_type(8)));   // 8 x bf16
typedef float  ffrag __attribute__((ext_vector_type(4)));   // mfma acc
typedef float  f4    __attribute__((ext_vector_type(4)));
typedef short  s4v   __attribute__((ext_vector_type(4)));   // 4 x bf16

#define DEV static __device__ __forceinline__
#define Hn 768
#define FLS 132   // f32 epilogue bounce row stride (pad: 128 + 4)

DEV unsigned short f2bf(float f) {
  unsigned u = __float_as_uint(f);
  u += 0x7fffu + ((u >> 16) & 1u);            // round-to-nearest-even
  return (unsigned short)(u >> 16);
}
DEV float bf2f(unsigned short s) { return __uint_as_float(((unsigned)s) << 16); }

DEV ffrag mfma16(bfrag a, bfrag b, ffrag c) {
  return __builtin_amdgcn_mfma_f32_16x16x32_bf16(a, b, c, 0, 0, 0);
}

DEV void glds16(const unsigned short* g, unsigned short* l) {
  __builtin_amdgcn_global_load_lds(
      (const __attribute__((address_space(1))) unsigned int*)g,
      (__attribute__((address_space(3))) unsigned int*)l, 16, 0, 0);
}

template<int N> DEV void vwait() {
  if constexpr (N == 0)      asm volatile("s_waitcnt vmcnt(0)" ::: "memory");
  else if constexpr (N == 4) asm volatile("s_waitcnt vmcnt(4)" ::: "memory");
  else if constexpr (N == 8) asm volatile("s_waitcnt vmcnt(8)" ::: "memory");
}

union BF8 { bfrag v; unsigned short u[8]; };

// ---------------------------------------------------------------------------
// k_abuild: gridDim = (768, 4); task = blockIdx.y
__global__ __launch_bounds__(256) void k_abuild(
    const float* __restrict__ U, const float* __restrict__ V,
    const float* __restrict__ S, const float* __restrict__ Bm,
    const float* __restrict__ Cm, const float* __restrict__ gw,
    float* __restrict__ Af, float* __restrict__ AfT,
    unsigned short* __restrict__ Abf,
    unsigned short* __restrict__ Bmb, unsigned short* __restrict__ Cmb,
    unsigned short* __restrict__ gwb, unsigned short* __restrict__ zp) {
  int i = blockIdx.x;
  int task = blockIdx.y;
  if (task == 0) {
    float u0 = U[i*4+0], u1 = U[i*4+1], u2 = U[i*4+2], u3 = U[i*4+3];
    for (int j = threadIdx.x; j < Hn; j += 256) {
      float a = u0*V[j*4+0] + u1*V[j*4+1] + u2*V[j*4+2] + u3*V[j*4+3]
              + S[i*Hn+j] - S[j*Hn+i];
      if (i == j) a += -(float)(i+1) / 768.0f;
      Af[i*Hn+j]  = a;
      AfT[j*Hn+i] = a;
      Abf[i*Hn+j] = f2bf(a);
    }
    if (i == 0) for (int j = threadIdx.x; j < 1024; j += 256) zp[j] = 0;
  } else {
    const float* src = (task==1) ? Bm : (task==2) ? Cm : gw;
    unsigned short* dst = (task==1) ? Bmb : (task==2) ? Cmb : gwb;
    for (int j = threadIdx.x; j < Hn; j += 256) dst[i*Hn+j] = f2bf(src[i*Hn+j]);
  }
}

// ---------------------------------------------------------------------------
// k_rms: one wave per row (row = b*2048 + t); write xn in (t,b) order, bf16.
__global__ __launch_bounds__(256) void k_rms(
    const float* __restrict__ x, const float* __restrict__ scale,
    unsigned short* __restrict__ xn) {
  int row  = blockIdx.x * 4 + (threadIdx.x >> 6);
  int lane = threadIdx.x & 63;
  int b = row >> 11, t = row & 2047;
  const float* xr = x + (long)row * Hn;
  float v[12];
  float ss = 0.f;
#pragma unroll
  for (int j = 0; j < 12; ++j) { v[j] = xr[lane + j*64]; ss += v[j]*v[j]; }
#pragma unroll
  for (int off = 1; off < 64; off <<= 1) ss += __shfl_xor(ss, off);
  float inv = 1.0f / sqrtf(ss / 768.0f + 1e-8f);
  unsigned short* dst = xn + ((long)t * 8 + b) * Hn;
#pragma unroll
  for (int j = 0; j < 12; ++j) dst[lane + j*64] = f2bf(v[j] * inv * scale[lane + j*64]);
}

// ---------------------------------------------------------------------------
// k_sq: Z = X @ X, hi/lo bf16 (3 passes). Writes Z rm + Z^T rm f32 + bf16.
// grid (12, 6), 512 thr, tile 64x128.
__global__ __launch_bounds__(512) void k_sq(
    const float* __restrict__ X, const float* __restrict__ XT,
    float* __restrict__ Z, float* __restrict__ ZT,
    unsigned short* __restrict__ Zbf) {
  int tid = threadIdx.x, lane = tid & 63, w = tid >> 6;
  int mw = w >> 2, nw = w & 3, l15 = lane & 15, lhi = lane >> 4;
  int rb = blockIdx.x * 64, cb = blockIdx.y * 128;
  ffrag acc[2][2] = {};
  for (int kt = 0; kt < 24; ++kt) {
    int k0 = kt*32 + lhi*8;
    BF8 ah[2], al[2], bh[2], bl[2];
#pragma unroll
    for (int mt = 0; mt < 2; ++mt) {
      const f4* p = (const f4*)(X + (long)(rb + mw*32 + mt*16 + l15) * Hn + k0);
      f4 x0 = p[0], x1 = p[1];
#pragma unroll
      for (int j = 0; j < 8; ++j) {
        float f = (j < 4) ? x0[j] : x1[j-4];
        unsigned short h = f2bf(f);
        ah[mt].u[j] = h; al[mt].u[j] = f2bf(f - bf2f(h));
      }
    }
#pragma unroll
    for (int nt = 0; nt < 2; ++nt) {
      const f4* p = (const f4*)(XT + (long)(cb + nw*32 + nt*16 + l15) * Hn + k0);
      f4 x0 = p[0], x1 = p[1];
#pragma unroll
      for (int j = 0; j < 8; ++j) {
        float f = (j < 4) ? x0[j] : x1[j-4];
        unsigned short h = f2bf(f);
        bh[nt].u[j] = h; bl[nt].u[j] = f2bf(f - bf2f(h));
      }
    }
#pragma unroll
    for (int mt = 0; mt < 2; ++mt)
#pragma unroll
      for (int nt = 0; nt < 2; ++nt) {
        acc[mt][nt] = mfma16(ah[mt].v, bh[nt].v, acc[mt][nt]);
        acc[mt][nt] = mfma16(ah[mt].v, bl[nt].v, acc[mt][nt]);
        acc[mt][nt] = mfma16(al[mt].v, bh[nt].v, acc[mt][nt]);
      }
  }
#pragma unroll
  for (int mt = 0; mt < 2; ++mt)
#pragma unroll
    for (int nt = 0; nt < 2; ++nt)
#pragma unroll
      for (int q = 0; q < 4; ++q) {
        int grow = rb + mw*32 + mt*16 + lhi*4 + q;
        int gcol = cb + nw*32 + nt*16 + l15;
        float vv = acc[mt][nt][q];
        Z[(long)grow*Hn + gcol] = vv;
        ZT[(long)gcol*Hn + grow] = vv;
        Zbf[(long)grow*Hn + gcol] = f2bf(vv);
      }
}

// ---------------------------------------------------------------------------
// k_gemm<MODE>: 128x128 tile, BK=32, 24 K-steps, 256 thr (4 waves, 2x2 of
// 64x64). Chunk swizzle c^((r^(r>>2))&3) on both glds source and LDS read.
// MODE 0: outb = [res +] A0[row -/+ sh] @ B0^T ; dup -> also write +16384.
//         3-buf ring, steady vmcnt(4).
// MODE 1: outb[r] = res[r]+res[r+16384] + (A0[r-sh] + A0[r+16384+sh]) @ B0^T
// MODE 2: outf = x + alpha*0.5*(A0@B0^T) * sigmoid(A1@B1^T + gb)  (row=t*8+b)
template<int MODE>
__global__ __launch_bounds__(256) void k_gemm(
    const unsigned short* __restrict__ A0s, const unsigned short* __restrict__ A1s,
    const unsigned short* __restrict__ B0s, const unsigned short* __restrict__ B1s,
    const unsigned short* __restrict__ res, unsigned short* __restrict__ outb,
    const unsigned short* __restrict__ zp, int sh, int dup,
    const float* __restrict__ gb, const float* __restrict__ alpha,
    const float* __restrict__ x, float* __restrict__ outf) {
  constexpr int NA   = (MODE == 0) ? 1 : 2;    // A streams
  constexpr int NB   = (MODE == 2) ? 2 : 1;    // B streams
  constexpr int NT   = NA + NB;                // tiles per step
  constexpr int NBUF = (MODE == 0) ? 3 : 2;    // LDS ring depth
  constexpr int NL   = 2 * NT;                 // glds16 per wave per stage

  __shared__ __align__(16) char smem[NBUF * NT * 8192];
  unsigned short* ldsb = (unsigned short*)smem;

  const int tid = threadIdx.x, lane = tid & 63, w = tid >> 6;
  const int l15 = lane & 15, lhi = lane >> 4;
  const int wr = w >> 1, wc = w & 1;

  // XCD-aware bijective block swizzle (m204), col-fast decompose (ncol=6).
  const int nwg = gridDim.x;
  const int q8 = nwg >> 3, r8 = nwg & 7, xcd = blockIdx.x & 7, fo = blockIdx.x >> 3;
  const int wg = (xcd < r8 ? xcd*(q8+1) : r8*(q8+1) + (xcd - r8)*q8) + fo;
  const int cb = wg % 6, rbk = wg / 6;
  const long r0 = (long)rbk * 128;
  const long bc0 = (long)cb * 128;
  const int dir = (MODE == 0 && r0 >= 16384) ? 1 : 0;

  bool skip = false;
  if (MODE == 0 && sh > 0)
    skip = dir ? (r0 >= 32768 - sh) : (r0 + 128 <= sh);

  // staging geometry: inst = w*2+jj covers rows inst*16..+15 (1KB each);
  // lane: rowin = lane>>2, chunk ch = lane&3; source chunk c = ch ^ XS(r).
  const int rowin = lane >> 2, ch = lane & 3;
  long gA[NA][2]; bool vA[NA][2]; long gB[NB][2]; int lbase[2];
#pragma unroll
  for (int jj = 0; jj < 2; ++jj) {
    const int inst = w*2 + jj;
    const int r = inst*16 + rowin;
    const int c = ch ^ ((r ^ (r >> 2)) & 3);
    lbase[jj] = inst * 512;
#pragma unroll
    for (int s = 0; s < NA; ++s) {
      long gr; bool ok = true;
      if (MODE == 0) {
        gr = r0 + r + (dir ? sh : -sh);
        ok = dir ? (gr < 32768) : (gr >= 0);
      } else if (MODE == 1) {
        if (s == 0) { gr = r0 + r - sh; ok = (gr >= 0); }
        else        { gr = r0 + r + 16384 + sh; ok = (gr < 32768); }
      } else {
        gr = r0 + r;
      }
      vA[s][jj] = ok; gA[s][jj] = gr * Hn + c*8;
    }
#pragma unroll
    for (int s = 0; s < NB; ++s)
      gB[s][jj] = (bc0 + r) * Hn + c*8;
  }

  auto stage = [&](int buf, int kt) {
    const int ko = kt * 32;
    unsigned short* dst = ldsb + buf * (NT * 4096);
#pragma unroll
    for (int jj = 0; jj < 2; ++jj) {
#pragma unroll
      for (int s = 0; s < NA; ++s) {
        const unsigned short* src0 = (MODE == 2 && s == 1) ? A1s : A0s;
        const unsigned short* g = vA[s][jj] ? (src0 + gA[s][jj] + ko) : zp;
        glds16(g, dst + s*4096 + lbase[jj]);
      }
#pragma unroll
      for (int s = 0; s < NB; ++s) {
        const unsigned short* src0 = (s == 0) ? B0s : B1s;
        glds16(src0 + gB[s][jj] + ko, dst + (NA + s)*4096 + lbase[jj]);
      }
    }
  };

  ffrag acc[4][4] = {};
  ffrag accZ[(MODE == 2) ? 4 : 1][(MODE == 2) ? 4 : 1] = {};
  const int cx = (lhi ^ ((l15 ^ (l15 >> 2)) & 3)) * 8;   // swizzled read chunk

  if (!skip) {
    if (MODE == 0) {
      stage(0, 0); stage(1, 1);
      int cur = 0;
      for (int kt = 0; kt < 24; ++kt) {
        if (kt < 23) vwait<4>(); else vwait<0>();
        __builtin_amdgcn_s_barrier();           // tile kt visible to all waves
        if (kt + 2 <= 23) stage((kt + 2) % 3, kt + 2);  // after barrier: race-free
        const unsigned short* L = ldsb + cur * (NT * 4096);
        bfrag a0[4], b0[4];
#pragma unroll
        for (int mt = 0; mt < 4; ++mt)
          a0[mt] = *(const bfrag*)&L[(wr*64 + mt*16 + l15)*32 + cx];
#pragma unroll
        for (int nt = 0; nt < 4; ++nt)
          b0[nt] = *(const bfrag*)&L[4096 + (wc*64 + nt*16 + l15)*32 + cx];
#pragma unroll
        for (int mt = 0; mt < 4; ++mt)
#pragma unroll
          for (int nt = 0; nt < 4; ++nt)
            acc[mt][nt] = mfma16(a0[mt], b0[nt], acc[mt][nt]);
        cur = (cur == 2) ? 0 : cur + 1;
      }
    } else {
      stage(0, 0);
      int cur = 0;
      for (int kt = 0; kt < 24; ++kt) {
        vwait<0>();
        __builtin_amdgcn_s_barrier();
        if (kt < 23) stage(cur ^ 1, kt + 1);    // flies across compute(kt)
        const unsigned short* L = ldsb + cur * (NT * 4096);
        bfrag a[2][4], b0[4], b1[4];
#pragma unroll
        for (int mt = 0; mt < 4; ++mt) {
          const int row = wr*64 + mt*16 + l15;
          a[0][mt] = *(const bfrag*)&L[row*32 + cx];
          a[1][mt] = *(const bfrag*)&L[4096 + row*32 + cx];
        }
#pragma unroll
        for (int nt = 0; nt < 4; ++nt) {
          const int row = wc*64 + nt*16 + l15;
          b0[nt] = *(const bfrag*)&L[2*4096 + row*32 + cx];
          if (MODE == 2) b1[nt] = *(const bfrag*)&L[3*4096 + row*32 + cx];
        }
#pragma unroll
        for (int mt = 0; mt < 4; ++mt)
#pragma unroll
          for (int nt = 0; nt < 4; ++nt) {
            if (MODE == 1) {
              acc[mt][nt] = mfma16(a[0][mt], b0[nt], acc[mt][nt]);
              acc[mt][nt] = mfma16(a[1][mt], b0[nt], acc[mt][nt]);
            } else {
              acc[mt][nt]  = mfma16(a[0][mt], b0[nt], acc[mt][nt]);
              accZ[mt][nt] = mfma16(a[1][mt], b1[nt], accZ[mt][nt]);
            }
          }
        cur ^= 1;
      }
    }
  }

  // MODE2: fold sigmoid gate into acc in fragment layout (same lane->elem map)
  if (MODE == 2) {
    const float al = alpha[0];
    float gvals[4];
#pragma unroll
    for (int nt = 0; nt < 4; ++nt) gvals[nt] = gb[bc0 + wc*64 + nt*16 + l15];
#pragma unroll
    for (int mt = 0; mt < 4; ++mt)
#pragma unroll
      for (int nt = 0; nt < 4; ++nt)
#pragma unroll
        for (int q = 0; q < 4; ++q) {
          float z = accZ[mt][nt][q] + gvals[nt];
          float g = 1.0f / (1.0f + __expf(-z));
          acc[mt][nt][q] *= al * 0.5f * g;
        }
  }

  // ------ epilogue: acc -> LDS bounce (f32, pad FLS) -> vectorized I/O ------
  float* fl = (float*)smem;                 // 64 rows x FLS f32 = 33792 B
#pragma unroll
  for (int hh = 0; hh < 2; ++hh) {
    __syncthreads();
    if (wr == hh) {
#pragma unroll
      for (int mt = 0; mt < 4; ++mt)
#pragma unroll
        for (int nt = 0; nt < 4; ++nt)
#pragma unroll
          for (int q = 0; q < 4; ++q)
            fl[(mt*16 + lhi*4 + q)*FLS + wc*64 + nt*16 + l15] = acc[mt][nt][q];
    }
    __syncthreads();
    for (int i = tid; i < 2048; i += 256) {
      const int row = i >> 5;
      const int cc  = (i & 31) << 2;
      f4 v = *(const f4*)&fl[row*FLS + cc];
      const long grow = r0 + hh*64 + row;
      const long gcol = bc0 + cc;
      const long go = grow * Hn + gcol;
      if (MODE == 0) {
        if (res) {
          s4v rv = *(const s4v*)&res[go];
#pragma unroll
          for (int j = 0; j < 4; ++j) v[j] += bf2f(((unsigned short*)&rv)[j]);
        }
        s4v ov;
#pragma unroll
        for (int j = 0; j < 4; ++j) ((unsigned short*)&ov)[j] = f2bf(v[j]);
        *(s4v*)&outb[go] = ov;
        if (dup) *(s4v*)&outb[go + (long)16384*Hn] = ov;
      } else if (MODE == 1) {
        s4v ra = *(const s4v*)&res[go];
        s4v rb2 = *(const s4v*)&res[go + (long)16384*Hn];
#pragma unroll
        for (int j = 0; j < 4; ++j)
          v[j] += bf2f(((unsigned short*)&ra)[j]) + bf2f(((unsigned short*)&rb2)[j]);
        s4v ov;
#pragma unroll
        for (int j = 0; j < 4; ++j) ((unsigned short*)&ov)[j] = f2bf(v[j]);
        *(s4v*)&outb[go] = ov;
      } else {
        const long t = grow >> 3, b = grow & 7;
        const long o = (b*2048 + t)*Hn + gcol;
        f4 xv = *(const f4*)&x[o];
        f4 ov;
#pragma unroll
        for (int j = 0; j < 4; ++j) ov[j] = xv[j] + v[j];
        *(f4*)&outf[o] = ov;
      }
    }
  }
}

// ---------------------------------------------------------------------------
extern "C" void kernel_launch(void* const* d_in, const int* in_sizes, int n_in,
                              void* d_out, int out_size, void* d_ws, size_t ws_size,
                              hipStream_t stream) {
  const float* x     = (const float*)d_in[0];
  const float* scale = (const float*)d_in[1];
  const float* U     = (const float*)d_in[2];
  const float* V     = (const float*)d_in[3];
  const float* S     = (const float*)d_in[4];
  const float* Bm    = (const float*)d_in[5];
  const float* Cm    = (const float*)d_in[6];
  const float* gw    = (const float*)d_in[7];
  const float* gb    = (const float*)d_in[8];
  const float* alpha = (const float*)d_in[9];
  float* out = (float*)d_out;

  char* p = (char*)d_ws;
  auto alloc = [&](size_t sz) { char* r = p; p += (sz + 255) & ~(size_t)255; return r; };

  const size_t SZ_X  = (size_t)32768 * Hn * sizeof(unsigned short);  // 50.3MB
  const size_t SZ_BF = (size_t)16384 * Hn * sizeof(unsigned short);  // 25.2MB
  const size_t SZ_M  = (size_t)Hn * Hn * sizeof(float);              // 2.36MB
  const size_t SZ_MB = (size_t)Hn * Hn * sizeof(unsigned short);     // 1.18MB

  unsigned short* xn = (unsigned short*)alloc(SZ_BF);
  unsigned short* XA = (unsigned short*)alloc(SZ_X);
  unsigned short* XB = (unsigned short*)alloc(SZ_X);
  float* Af  = (float*)alloc(SZ_M);
  float* AfT = (float*)alloc(SZ_M);
  float* P1  = (float*)alloc(SZ_M);
  float* P1T = (float*)alloc(SZ_M);
  float* P2  = (float*)alloc(SZ_M);
  float* P2T = (float*)alloc(SZ_M);
  unsigned short* Abf = (unsigned short*)alloc(SZ_MB);
  unsigned short* Ab[10];                      // A^2..A^1024 bf16
  for (int i = 0; i < 10; ++i) Ab[i] = (unsigned short*)alloc(SZ_MB);
  unsigned short* Bmb = (unsigned short*)alloc(SZ_MB);
  unsigned short* Cmb = (unsigned short*)alloc(SZ_MB);
  unsigned short* gwb = (unsigned short*)alloc(SZ_MB);
  unsigned short* zp  = (unsigned short*)alloc(1024 * sizeof(unsigned short));

  if ((size_t)(p - (char*)d_ws) > ws_size) return;  // workspace too small

  k_abuild<<<dim3(768, 4), 256, 0, stream>>>(U, V, S, Bm, Cm, gw,
      Af, AfT, Abf, Bmb, Cmb, gwb, zp);
  k_rms<<<4096, 256, 0, stream>>>(x, scale, xn);

  // squaring chain: A -> A^2 -> ... -> A^1024 (bf16 emitted each step)
  const float* sx = Af; const float* sxt = AfT;
  float* za = P1; float* zat = P1T; float* zb = P2; float* zbt = P2T;
  for (int i = 0; i < 10; ++i) {
    k_sq<<<dim3(12, 6), 512, 0, stream>>>(sx, sxt, za, zat, Ab[i]);
    sx = za; sxt = zat;
    float* t1 = za; float* t2 = zat; za = zb; zat = zbt; zb = t1; zbt = t2;
  }

  // u = xn@Bm^T, duplicated into fwd+bwd halves of XA
  k_gemm<0><<<768, 256, 0, stream>>>(xn, nullptr, Bmb, nullptr, nullptr, XA,
      zp, 0, 1, nullptr, nullptr, nullptr, nullptr);

  // doubling levels k=1..512 (shift sh=8k rows)
  unsigned short* src = XA; unsigned short* dst = XB;
  for (int i = 0; i < 10; ++i) {
    const unsigned short* W = (i == 0) ? Abf : Ab[i-1];
    k_gemm<0><<<1536, 256, 0, stream>>>(src, nullptr, W, nullptr, src, dst,
        zp, 8 << i, 0, nullptr, nullptr, nullptr, nullptr);
    unsigned short* t = src; src = dst; dst = t;
  }
  // src holds X_1024 (both dirs). Last level (k=1024) + fwd/bwd sum -> Xsum:
  unsigned short* xsum = (src == XA) ? XB : XA;
  k_gemm<1><<<768, 256, 0, stream>>>(src, nullptr, Ab[9], nullptr, src, xsum,
      zp, 8192, 0, nullptr, nullptr, nullptr, nullptr);

  // out = x + alpha*0.5*(Xsum@Cm^T)*sigmoid(xn@gw^T+gb)   (fused dual GEMM)
  k_gemm<2><<<768, 256, 0, stream>>>(xsum, xn, Cmb, gwb, nullptr, nullptr,
      zp, 0, 0, gb, alpha, x, out);
}